// Round 14
// baseline (132.364 us; speedup 1.0000x reference)
//
#include <hip/hip_runtime.h>

#define Hd 512
#define N2d 16
#define Rd 32
#define Ld 4096
#define NCHUNK 128
#define CLEN (Ld / NCHUNK)        // 32
#define NCH (Hd * N2d)            // 8192 chains
#define NGRP 16                   // chunks per prefix group
#define NGROUPS (NCHUNK / NGRP)   // 8

// Layout note (r14): du and y1T are CHUNK-MAJOR: [c][h][l'] (l' = pos in
// chunk). Gives every k_chunk/k_corr thread a contiguous 256/64-B row
// (float4 ops) instead of 8-B loads strided by 4 KB. Same total sizes.

// ---------------------------------------------------------------------------
// Kernel 1: dt = softplus(u@xprojT@dtwT + b); writes du[c][h][l'] = (dt, u/dt).
// ---------------------------------------------------------------------------
__global__ __launch_bounds__(256) void k_dt(const float* __restrict__ u,
                                            const float* __restrict__ xproj_w,
                                            const float* __restrict__ dt_w,
                                            const float* __restrict__ dt_b,
                                            float2* __restrict__ du_out) {
    __shared__ float u_s[8][Hd];
    __shared__ float dtu_s[8][Rd];
    const int t = threadIdx.x;
    const int l0 = blockIdx.x * 8;
    const int cch = l0 >> 5;                  // chunk
    const int lp  = l0 & 31;                  // l' base (0,8,16,24)

    #pragma unroll
    for (int i = 0; i < 16; ++i) {
        int idx = t + i * 256;
        ((float*)u_s)[idx] = u[l0 * Hd + idx];
    }
    __syncthreads();

    const int r = t >> 3;
    const int j = t & 7;
    float part[8];
    #pragma unroll
    for (int l = 0; l < 8; ++l) part[l] = 0.f;
    for (int k = 0; k < 64; ++k) {
        float w = xproj_w[r * Hd + k * 8 + j];
        #pragma unroll
        for (int l = 0; l < 8; ++l) part[l] = fmaf(u_s[l][k * 8 + j], w, part[l]);
    }
    #pragma unroll
    for (int off = 1; off < 8; off <<= 1) {
        #pragma unroll
        for (int l = 0; l < 8; ++l) part[l] += __shfl_xor(part[l], off);
    }
    if (j == 0) {
        #pragma unroll
        for (int l = 0; l < 8; ++l) dtu_s[l][r] = part[l];
    }
    __syncthreads();

    #pragma unroll
    for (int hb = 0; hb < 2; ++hb) {
        int h = hb * 256 + t;
        float bias = dt_b[h];
        float acc[8];
        #pragma unroll
        for (int l = 0; l < 8; ++l) acc[l] = bias;
        #pragma unroll
        for (int rb = 0; rb < 8; ++rb) {
            float4 w = *(const float4*)&dt_w[h * Rd + rb * 4];
            #pragma unroll
            for (int l = 0; l < 8; ++l) {
                acc[l] = fmaf(dtu_s[l][rb * 4 + 0], w.x, acc[l]);
                acc[l] = fmaf(dtu_s[l][rb * 4 + 1], w.y, acc[l]);
                acc[l] = fmaf(dtu_s[l][rb * 4 + 2], w.z, acc[l]);
                acc[l] = fmaf(dtu_s[l][rb * 4 + 3], w.w, acc[l]);
            }
        }
        float2 vals[8];
        #pragma unroll
        for (int l = 0; l < 8; ++l) {
            float x = acc[l];
            float sp = fmaxf(x, 0.f) + log1pf(__expf(-fabsf(x)));  // softplus
            float uv = u_s[l][h];
            float us = uv * __builtin_amdgcn_rcpf(fmaxf(sp, 1e-30f));
            vals[l] = make_float2(sp, us);
        }
        float4* d4 = (float4*)&du_out[((size_t)cch * Hd + h) * CLEN + lp];
        #pragma unroll
        for (int i = 0; i < 4; ++i)
            d4[i] = make_float4(vals[2 * i].x, vals[2 * i].y,
                                vals[2 * i + 1].x, vals[2 * i + 1].y);
    }
}

// ---------------------------------------------------------------------------
// Kernel 2: per-chunk local scan (h0=0), r9 geometry (CLEN=32, 4 n/thread,
// register double-buffer). Chunk-major du: each thread's 32 steps are one
// contiguous 256-B row -> 16 float4 loads. y1T written 8-steps-at-a-time as
// 4 contiguous float4 by the q==0 lane. Emits Sb (float2) + Tc (chunk dt-sum);
// P = exp(A*Tc) is recomputed in k_comb (bit-identical, no PS round-trip).
// ---------------------------------------------------------------------------
__global__ __launch_bounds__(256) void k_chunk(const float2* __restrict__ du,
        const float* __restrict__ A_log, const float* __restrict__ A_im,
        const float* __restrict__ B_param, const float* __restrict__ C_param,
        const float* __restrict__ Dp,
        float2* __restrict__ Sb, float* __restrict__ Tc,
        float2* __restrict__ y1T) {
    const int t = threadIdx.x;
    const int q = t & 3;
    const int hh = blockIdx.y * 64 + (t >> 2);
    const int c = blockIdx.x;
    const int hnb = hh * N2d + q * 4;

    const float2* rowb = du + ((size_t)c * Hd + hh) * CLEN;
    float2* y1row = y1T + ((size_t)c * Hd + hh) * CLEN;

    float alog[4], Aim[4];
    #pragma unroll
    for (int j = 0; j < 4; ++j) {
        alog[j] = A_log[hnb + j];
        Aim[j] = A_im[hnb + j];
    }
    float d1 = Aim[1] - Aim[0], d2 = Aim[2] - Aim[1], d3 = Aim[3] - Aim[2];
    const bool fast = (alog[1] == alog[0]) && (alog[2] == alog[0]) &&
                      (alog[3] == alog[0]) && (d1 == d2) && (d2 == d3);
    float Are[4];
    if (fast) {                     // branch (not ternary) so 3 exps vanish
        Are[0] = -__expf(alog[0]);
        Are[1] = Are[2] = Are[3] = Are[0];
    } else {
        #pragma unroll
        for (int j = 0; j < 4; ++j) Are[j] = -__expf(alog[j]);
    }
    float BAr[4], BAi[4], Cre[4], Cim[4];
    #pragma unroll
    for (int j = 0; j < 4; ++j) {
        int hn = hnb + j;
        float Bre = B_param[2 * hn];
        float Bim = B_param[2 * hn + 1];
        float inv = __builtin_amdgcn_rcpf(Are[j] * Are[j] + Aim[j] * Aim[j]);
        BAr[j] = (Bre * Are[j] + Bim * Aim[j]) * inv;   // Bc*conj(A)/|A|^2
        BAi[j] = (Bim * Are[j] - Bre * Aim[j]) * inv;
        Cre[j] = C_param[2 * hn];
        Cim[j] = C_param[2 * hn + 1];
    }
    const float Dv = Dp[hh];

    float sr[4] = {0.f, 0.f, 0.f, 0.f}, si[4] = {0.f, 0.f, 0.f, 0.f};
    float sdt = 0.f;

    float2 b0[8], b1[8];

    #define LOADB(buf, bb)                                                     \
        { const float4* r4 = (const float4*)(rowb + (bb) * 8);                 \
          _Pragma("unroll")                                                    \
          for (int k4 = 0; k4 < 4; ++k4) {                                     \
              float4 v = r4[k4];                                               \
              buf[2 * k4]     = make_float2(v.x, v.y);                         \
              buf[2 * k4 + 1] = make_float2(v.z, v.w);                         \
          } }

    #define YWRITE(bb)                                                         \
        if (q == 0) {                                                          \
            float4* y4 = (float4*)(y1row + (bb) * 8);                          \
            _Pragma("unroll")                                                  \
            for (int i = 0; i < 4; ++i)                                        \
                y4[i] = make_float4(yb[2 * i].x, yb[2 * i].y,                  \
                                    yb[2 * i + 1].x, yb[2 * i + 1].y);         \
        }

    if (fast) {
        const float Are0 = Are[0], Aim0 = Aim[0], dA = Aim[1] - Aim[0];
        #define STEPF(buf, bb)                                                 \
            { float2 yb[8];                                                    \
              _Pragma("unroll")                                                \
              for (int k = 0; k < 8; ++k) {                                    \
                float dtv = buf[k].x, us = buf[k].y;                           \
                sdt += dtv;                                                    \
                float er = __expf(dtv * Are0);                                 \
                float s0, c0, sd, cd;                                          \
                __sincosf(dtv * Aim0, &s0, &c0);                               \
                __sincosf(dtv * dA, &sd, &cd);                                 \
                float ar = er * c0, ai = er * s0;                              \
                float yv = 0.f;                                                \
                _Pragma("unroll")                                              \
                for (int jj = 0; jj < 4; ++jj) {                               \
                    float gr = fmaf(ar, us, -us);                              \
                    float gi = ai * us;                                        \
                    float nr = fmaf(ar, sr[jj], fmaf(-ai, si[jj],              \
                                 fmaf(gr, BAr[jj], -gi * BAi[jj])));           \
                    float ni = fmaf(ar, si[jj], fmaf( ai, sr[jj],              \
                                 fmaf(gr, BAi[jj],  gi * BAr[jj])));           \
                    sr[jj] = nr; si[jj] = ni;                                  \
                    yv = fmaf(nr, Cre[jj], fmaf(-ni, Cim[jj], yv));            \
                    if (jj < 3) {                                              \
                        float tr = fmaf(ar, cd, -ai * sd);                     \
                        ai = fmaf(ai, cd, ar * sd);                            \
                        ar = tr;                                               \
                    }                                                          \
                }                                                              \
                yv += __shfl_xor(yv, 1);                                       \
                yv += __shfl_xor(yv, 2);                                       \
                yb[k] = make_float2(fmaf(dtv * us, Dv, yv), sdt);              \
              }                                                                \
              YWRITE(bb) }
        LOADB(b0, 0);
        LOADB(b1, 1); STEPF(b0, 0);
        LOADB(b0, 2); STEPF(b1, 1);
        LOADB(b1, 3); STEPF(b0, 2);
        STEPF(b1, 3);
        #undef STEPF
    } else {
        #define STEPS(buf, bb)                                                 \
            { float2 yb[8];                                                    \
              _Pragma("unroll")                                                \
              for (int k = 0; k < 8; ++k) {                                    \
                float dtv = buf[k].x, us = buf[k].y;                           \
                sdt += dtv;                                                    \
                float yv = 0.f;                                                \
                _Pragma("unroll")                                              \
                for (int jj = 0; jj < 4; ++jj) {                               \
                    float er = __expf(dtv * Are[jj]);                          \
                    float s, cc;                                               \
                    __sincosf(dtv * Aim[jj], &s, &cc);                         \
                    float ar = er * cc, ai = er * s;                           \
                    float gr = fmaf(ar, us, -us);                              \
                    float gi = ai * us;                                        \
                    float nr = fmaf(ar, sr[jj], fmaf(-ai, si[jj],              \
                                 fmaf(gr, BAr[jj], -gi * BAi[jj])));           \
                    float ni = fmaf(ar, si[jj], fmaf( ai, sr[jj],              \
                                 fmaf(gr, BAi[jj],  gi * BAr[jj])));           \
                    sr[jj] = nr; si[jj] = ni;                                  \
                    yv = fmaf(nr, Cre[jj], fmaf(-ni, Cim[jj], yv));            \
                }                                                              \
                yv += __shfl_xor(yv, 1);                                       \
                yv += __shfl_xor(yv, 2);                                       \
                yb[k] = make_float2(fmaf(dtv * us, Dv, yv), sdt);              \
              }                                                                \
              YWRITE(bb) }
        LOADB(b0, 0);
        LOADB(b1, 1); STEPS(b0, 0);
        LOADB(b0, 2); STEPS(b1, 1);
        LOADB(b1, 3); STEPS(b0, 2);
        STEPS(b1, 3);
        #undef STEPS
    }
    #undef LOADB
    #undef YWRITE

    int base = c * NCH + hnb;
    #pragma unroll
    for (int jj = 0; jj < 4; ++jj)
        Sb[base + jj] = make_float2(sr[jj], si[jj]);
    if (q == 0) Tc[hh * NCHUNK + c] = sdt;
}

// ---------------------------------------------------------------------------
// Kernel 3: fused prefix-combine. Block = {32 chains x 8 groups} (256 thr).
// P = exp(A*Tc) recomputed from the scalar Tc. Emits W[c][chain] = C * h0(c).
// ---------------------------------------------------------------------------
__global__ __launch_bounds__(256) void k_comb(const float2* __restrict__ Sb,
        const float* __restrict__ Tc, const float* __restrict__ A_log,
        const float* __restrict__ A_im, const float* __restrict__ C_param,
        float2* __restrict__ W) {
    __shared__ float4 agg_s[32][NGROUPS + 1];   // [chain_l][g], pad
    __shared__ float Tc_s[2][NCHUNK];
    const int t = threadIdx.x;
    const int g = t >> 5;                       // 0..7
    const int cl = t & 31;
    const int chain = blockIdx.x * 32 + cl;
    const int h0 = blockIdx.x * 2;              // block spans h0, h0+1

    {
        int cc = t & 127;
        int hs = t >> 7;
        Tc_s[hs][cc] = Tc[(h0 + hs) * NCHUNK + cc];
    }
    __syncthreads();

    const int hsel = cl >> 4;
    const float Are = -__expf(A_log[chain]);
    const float Aim = A_im[chain];

    float2 s[NGRP];
    float pr[NGRP], pi[NGRP];
    #pragma unroll
    for (int i = 0; i < NGRP; ++i) {
        int c = g * NGRP + i;
        s[i] = Sb[c * NCH + chain];
        float T = Tc_s[hsel][c];
        float er = __expf(Are * T);
        float sn, cs;
        __sincosf(Aim * T, &sn, &cs);
        pr[i] = er * cs;
        pi[i] = er * sn;
    }

    float Pr = 1.f, Pi = 0.f, Hr = 0.f, Hi = 0.f;
    #pragma unroll
    for (int i = 0; i < NGRP; ++i) {
        float nhr = fmaf(pr[i], Hr, fmaf(-pi[i], Hi, s[i].x));
        float nhi = fmaf(pr[i], Hi, fmaf( pi[i], Hr, s[i].y));
        float npr = fmaf(pr[i], Pr, -pi[i] * Pi);
        float npi = fmaf(pr[i], Pi,  pi[i] * Pr);
        Hr = nhr; Hi = nhi; Pr = npr; Pi = npi;
    }
    agg_s[cl][g] = make_float4(Pr, Pi, Hr, Hi);
    __syncthreads();

    // exclusive cross-group prefix (g uniform across each 32-lane slice)
    float hr = 0.f, hi = 0.f;
    for (int j = 0; j < g; ++j) {
        float4 a = agg_s[cl][j];
        float nr = fmaf(a.x, hr, fmaf(-a.y, hi, a.z));
        float ni = fmaf(a.x, hi, fmaf( a.y, hr, a.w));
        hr = nr; hi = ni;
    }

    const float Cr = C_param[2 * chain];
    const float Ci = C_param[2 * chain + 1];
    #pragma unroll
    for (int i = 0; i < NGRP; ++i) {
        int c = g * NGRP + i;
        W[c * NCH + chain] = make_float2(fmaf(Cr, hr, -Ci * hi),
                                         fmaf(Cr, hi,  Ci * hr));
        float nr = fmaf(pr[i], hr, fmaf(-pi[i], hi, s[i].x));
        float ni = fmaf(pr[i], hi, fmaf( pi[i], hr, s[i].y));
        hr = nr; hi = ni;
    }
}

// ---------------------------------------------------------------------------
// Kernel 4: correction pass. Thread owns one h x 8 l'; chunk-major y1T makes
// its 8 entries one contiguous 64-B block (4 float4); W row = 8 float4.
//   y = y1 + Re( sum_n exp(A_n*T_l) * W_n )
// ---------------------------------------------------------------------------
__global__ __launch_bounds__(256) void k_corr(const float2* __restrict__ y1T,
        const float* __restrict__ A_log, const float* __restrict__ A_im,
        const float2* __restrict__ W, float* __restrict__ out) {
    const int t = threadIdx.x;
    const int c = blockIdx.x;        // chunk
    const int hl = t & 63;
    const int h = blockIdx.y * 64 + hl;
    const int lb = t >> 6;           // 0..3
    const int l0 = c * CLEN + lb * 8;
    const int hn0 = h * N2d;

    float2 yt[8];
    {
        const float4* y4 = (const float4*)(y1T + ((size_t)c * Hd + h) * CLEN + lb * 8);
        #pragma unroll
        for (int i = 0; i < 4; ++i) {
            float4 v = y4[i];
            yt[2 * i]     = make_float2(v.x, v.y);
            yt[2 * i + 1] = make_float2(v.z, v.w);
        }
    }

    float2 w[N2d];
    {
        const float4* w4 = reinterpret_cast<const float4*>(&W[c * NCH + hn0]);
        #pragma unroll
        for (int n = 0; n < 8; ++n) {
            float4 v = w4[n];
            w[2 * n]     = make_float2(v.x, v.y);
            w[2 * n + 1] = make_float2(v.z, v.w);
        }
    }

    float alog[N2d], aim[N2d];
    #pragma unroll
    for (int n = 0; n < N2d; ++n) {
        alog[n] = A_log[hn0 + n];
        aim[n] = A_im[hn0 + n];
    }
    float dA = aim[1] - aim[0];
    bool fast = true;
    #pragma unroll
    for (int n = 1; n < N2d; ++n)
        fast = fast && (alog[n] == alog[0]) && (aim[n] - aim[n - 1] == dA);

    if (fast) {
        const float Are0 = -__expf(alog[0]);
        const float Aim0 = aim[0];
        #pragma unroll
        for (int k = 0; k < 8; ++k) {
            float T = yt[k].y;
            float er = __expf(Are0 * T);
            float s0, c0, sd, cd;
            __sincosf(Aim0 * T, &s0, &c0);
            __sincosf(dA * T, &sd, &cd);
            float ar = er * c0, ai = er * s0;
            float corr = 0.f;
            #pragma unroll
            for (int n = 0; n < N2d; ++n) {
                corr = fmaf(ar, w[n].x, fmaf(-ai, w[n].y, corr));
                if (n < N2d - 1) {
                    float tr = fmaf(ar, cd, -ai * sd);
                    ai = fmaf(ai, cd, ar * sd);
                    ar = tr;
                }
            }
            out[(l0 + k) * Hd + h] = yt[k].x + corr;
        }
    } else {
        float are[N2d];
        #pragma unroll
        for (int n = 0; n < N2d; ++n) are[n] = -__expf(alog[n]);
        #pragma unroll
        for (int k = 0; k < 8; ++k) {
            float T = yt[k].y;
            float corr = 0.f;
            #pragma unroll
            for (int n = 0; n < N2d; ++n) {
                float er = __expf(are[n] * T);
                float s, cc;
                __sincosf(aim[n] * T, &s, &cc);
                corr = fmaf(er * cc, w[n].x, fmaf(-er * s, w[n].y, corr));
            }
            out[(l0 + k) * Hd + h] = yt[k].x + corr;
        }
    }
}

extern "C" void kernel_launch(void* const* d_in, const int* in_sizes, int n_in,
                              void* d_out, int out_size, void* d_ws, size_t ws_size,
                              hipStream_t stream) {
    const float* u        = (const float*)d_in[0];
    const float* A_log    = (const float*)d_in[1];
    const float* A_im     = (const float*)d_in[2];
    const float* B_param  = (const float*)d_in[3];
    const float* C_param  = (const float*)d_in[4];
    const float* Dp       = (const float*)d_in[5];
    const float* dt_w     = (const float*)d_in[6];
    const float* dt_b     = (const float*)d_in[7];
    const float* xproj_w  = (const float*)d_in[8];

    // ws layout: du[L*H f2, chunk-major] | Sb[NCHUNK*NCH f2] | W[NCHUNK*NCH f2]
    //          | y1T[L*H f2, chunk-major] | Tc[Hd*NCHUNK f]
    float2* du  = (float2*)d_ws;
    float2* Sb  = du + (size_t)Ld * Hd;
    float2* W   = Sb + (size_t)NCHUNK * NCH;
    float2* y1T = W + (size_t)NCHUNK * NCH;
    float*  Tc  = (float*)(y1T + (size_t)Ld * Hd);
    float*  out = (float*)d_out;

    k_dt<<<Ld / 8, 256, 0, stream>>>(u, xproj_w, dt_w, dt_b, du);
    dim3 g2(NCHUNK, Hd / 64);
    k_chunk<<<g2, 256, 0, stream>>>(du, A_log, A_im, B_param, C_param, Dp,
                                    Sb, Tc, y1T);
    k_comb<<<NCH / 32, 256, 0, stream>>>(Sb, Tc, A_log, A_im, C_param, W);
    k_corr<<<g2, 256, 0, stream>>>(y1T, A_log, A_im, W, out);
}

// Round 15
// 130.374 us; speedup vs baseline: 1.0153x; 1.0153x over previous
//
#include <hip/hip_runtime.h>

#define Hd 512
#define N2d 16
#define Rd 32
#define Ld 4096
#define NCHUNK 128
#define CLEN (Ld / NCHUNK)        // 32
#define NCH (Hd * N2d)            // 8192 chains
#define NGRP 16                   // chunks per prefix group
#define NGROUPS (NCHUNK / NGRP)   // 8

// Layout note: du and y1T are CHUNK-MAJOR: [c][h][l'] (l' = pos in chunk).
// k_chunk/k_corr threads get contiguous 256/64-B rows. k_dt writes go
// through an LDS transpose so its stores stay coalesced (r14's direct
// scattered stores caused 2x write amplification, WRITE_SIZE 32 MB).

// ---------------------------------------------------------------------------
// Kernel 1: dt = softplus(u@xprojT@dtwT + b); writes du[c][h][l'] = (dt, u/dt).
// ---------------------------------------------------------------------------
__global__ __launch_bounds__(256) void k_dt(const float* __restrict__ u,
                                            const float* __restrict__ xproj_w,
                                            const float* __restrict__ dt_w,
                                            const float* __restrict__ dt_b,
                                            float2* __restrict__ du_out) {
    __shared__ float u_s[8][Hd];
    __shared__ float dtu_s[8][Rd];
    __shared__ float2 st_s[256][9];           // write-staging, pad -> minor conflicts
    const int t = threadIdx.x;
    const int l0 = blockIdx.x * 8;
    const int cch = l0 >> 5;                  // chunk
    const int lp  = l0 & 31;                  // l' base (0,8,16,24)

    #pragma unroll
    for (int i = 0; i < 16; ++i) {
        int idx = t + i * 256;
        ((float*)u_s)[idx] = u[l0 * Hd + idx];
    }
    __syncthreads();

    const int r = t >> 3;
    const int j = t & 7;
    float part[8];
    #pragma unroll
    for (int l = 0; l < 8; ++l) part[l] = 0.f;
    for (int k = 0; k < 64; ++k) {
        float w = xproj_w[r * Hd + k * 8 + j];
        #pragma unroll
        for (int l = 0; l < 8; ++l) part[l] = fmaf(u_s[l][k * 8 + j], w, part[l]);
    }
    #pragma unroll
    for (int off = 1; off < 8; off <<= 1) {
        #pragma unroll
        for (int l = 0; l < 8; ++l) part[l] += __shfl_xor(part[l], off);
    }
    if (j == 0) {
        #pragma unroll
        for (int l = 0; l < 8; ++l) dtu_s[l][r] = part[l];
    }
    __syncthreads();

    #pragma unroll
    for (int hb = 0; hb < 2; ++hb) {
        int h = hb * 256 + t;
        float bias = dt_b[h];
        float acc[8];
        #pragma unroll
        for (int l = 0; l < 8; ++l) acc[l] = bias;
        #pragma unroll
        for (int rb = 0; rb < 8; ++rb) {
            float4 w = *(const float4*)&dt_w[h * Rd + rb * 4];
            #pragma unroll
            for (int l = 0; l < 8; ++l) {
                acc[l] = fmaf(dtu_s[l][rb * 4 + 0], w.x, acc[l]);
                acc[l] = fmaf(dtu_s[l][rb * 4 + 1], w.y, acc[l]);
                acc[l] = fmaf(dtu_s[l][rb * 4 + 2], w.z, acc[l]);
                acc[l] = fmaf(dtu_s[l][rb * 4 + 3], w.w, acc[l]);
            }
        }
        #pragma unroll
        for (int l = 0; l < 8; ++l) {
            float x = acc[l];
            float sp = fmaxf(x, 0.f) + log1pf(__expf(-fabsf(x)));  // softplus
            float uv = u_s[l][h];
            float us = uv * __builtin_amdgcn_rcpf(fmaxf(sp, 1e-30f));
            st_s[t][l] = make_float2(sp, us);
        }
        __syncthreads();
        // cooperative coalesced write of the [256 h][8 l'] half-region:
        // 1024 float4, 4/thread; 4 consecutive float4 cover each 64-B row seg.
        {
            float2* dub = du_out + ((size_t)cch * Hd + hb * 256) * CLEN + lp;
            #pragma unroll
            for (int i = 0; i < 4; ++i) {
                int flat = i * 256 + t;       // 0..1023
                int row = flat >> 2;          // 4 float4 per row
                int col = flat & 3;
                float2 a = st_s[row][col * 2];
                float2 b = st_s[row][col * 2 + 1];
                *(float4*)(dub + (size_t)row * CLEN + col * 2) =
                    make_float4(a.x, a.y, b.x, b.y);
            }
        }
        __syncthreads();                      // st_s reused by next hb
    }
}

// ---------------------------------------------------------------------------
// Kernel 2: per-chunk local scan (h0=0), r9 geometry (CLEN=32, 4 n/thread,
// register double-buffer). Chunk-major du: each thread's 32 steps are one
// contiguous 256-B row -> 16 float4 loads. y1T written 8-steps-at-a-time as
// 4 contiguous float4 by the q==0 lane. Emits Sb (float2) + Tc (chunk dt-sum);
// P = exp(A*Tc) is recomputed in k_comb (bit-identical, no PS round-trip).
// ---------------------------------------------------------------------------
__global__ __launch_bounds__(256) void k_chunk(const float2* __restrict__ du,
        const float* __restrict__ A_log, const float* __restrict__ A_im,
        const float* __restrict__ B_param, const float* __restrict__ C_param,
        const float* __restrict__ Dp,
        float2* __restrict__ Sb, float* __restrict__ Tc,
        float2* __restrict__ y1T) {
    const int t = threadIdx.x;
    const int q = t & 3;
    const int hh = blockIdx.y * 64 + (t >> 2);
    const int c = blockIdx.x;
    const int hnb = hh * N2d + q * 4;

    const float2* rowb = du + ((size_t)c * Hd + hh) * CLEN;
    float2* y1row = y1T + ((size_t)c * Hd + hh) * CLEN;

    float alog[4], Aim[4];
    #pragma unroll
    for (int j = 0; j < 4; ++j) {
        alog[j] = A_log[hnb + j];
        Aim[j] = A_im[hnb + j];
    }
    float d1 = Aim[1] - Aim[0], d2 = Aim[2] - Aim[1], d3 = Aim[3] - Aim[2];
    const bool fast = (alog[1] == alog[0]) && (alog[2] == alog[0]) &&
                      (alog[3] == alog[0]) && (d1 == d2) && (d2 == d3);
    float Are[4];
    if (fast) {                     // branch (not ternary) so 3 exps vanish
        Are[0] = -__expf(alog[0]);
        Are[1] = Are[2] = Are[3] = Are[0];
    } else {
        #pragma unroll
        for (int j = 0; j < 4; ++j) Are[j] = -__expf(alog[j]);
    }
    float BAr[4], BAi[4], Cre[4], Cim[4];
    #pragma unroll
    for (int j = 0; j < 4; ++j) {
        int hn = hnb + j;
        float Bre = B_param[2 * hn];
        float Bim = B_param[2 * hn + 1];
        float inv = __builtin_amdgcn_rcpf(Are[j] * Are[j] + Aim[j] * Aim[j]);
        BAr[j] = (Bre * Are[j] + Bim * Aim[j]) * inv;   // Bc*conj(A)/|A|^2
        BAi[j] = (Bim * Are[j] - Bre * Aim[j]) * inv;
        Cre[j] = C_param[2 * hn];
        Cim[j] = C_param[2 * hn + 1];
    }
    const float Dv = Dp[hh];

    float sr[4] = {0.f, 0.f, 0.f, 0.f}, si[4] = {0.f, 0.f, 0.f, 0.f};
    float sdt = 0.f;

    float2 b0[8], b1[8];

    #define LOADB(buf, bb)                                                     \
        { const float4* r4 = (const float4*)(rowb + (bb) * 8);                 \
          _Pragma("unroll")                                                    \
          for (int k4 = 0; k4 < 4; ++k4) {                                     \
              float4 v = r4[k4];                                               \
              buf[2 * k4]     = make_float2(v.x, v.y);                         \
              buf[2 * k4 + 1] = make_float2(v.z, v.w);                         \
          } }

    #define YWRITE(bb)                                                         \
        if (q == 0) {                                                          \
            float4* y4 = (float4*)(y1row + (bb) * 8);                          \
            _Pragma("unroll")                                                  \
            for (int i = 0; i < 4; ++i)                                        \
                y4[i] = make_float4(yb[2 * i].x, yb[2 * i].y,                  \
                                    yb[2 * i + 1].x, yb[2 * i + 1].y);         \
        }

    if (fast) {
        const float Are0 = Are[0], Aim0 = Aim[0], dA = Aim[1] - Aim[0];
        #define STEPF(buf, bb)                                                 \
            { float2 yb[8];                                                    \
              _Pragma("unroll")                                                \
              for (int k = 0; k < 8; ++k) {                                    \
                float dtv = buf[k].x, us = buf[k].y;                           \
                sdt += dtv;                                                    \
                float er = __expf(dtv * Are0);                                 \
                float s0, c0, sd, cd;                                          \
                __sincosf(dtv * Aim0, &s0, &c0);                               \
                __sincosf(dtv * dA, &sd, &cd);                                 \
                float ar = er * c0, ai = er * s0;                              \
                float yv = 0.f;                                                \
                _Pragma("unroll")                                              \
                for (int jj = 0; jj < 4; ++jj) {                               \
                    float gr = fmaf(ar, us, -us);                              \
                    float gi = ai * us;                                        \
                    float nr = fmaf(ar, sr[jj], fmaf(-ai, si[jj],              \
                                 fmaf(gr, BAr[jj], -gi * BAi[jj])));           \
                    float ni = fmaf(ar, si[jj], fmaf( ai, sr[jj],              \
                                 fmaf(gr, BAi[jj],  gi * BAr[jj])));           \
                    sr[jj] = nr; si[jj] = ni;                                  \
                    yv = fmaf(nr, Cre[jj], fmaf(-ni, Cim[jj], yv));            \
                    if (jj < 3) {                                              \
                        float tr = fmaf(ar, cd, -ai * sd);                     \
                        ai = fmaf(ai, cd, ar * sd);                            \
                        ar = tr;                                               \
                    }                                                          \
                }                                                              \
                yv += __shfl_xor(yv, 1);                                       \
                yv += __shfl_xor(yv, 2);                                       \
                yb[k] = make_float2(fmaf(dtv * us, Dv, yv), sdt);              \
              }                                                                \
              YWRITE(bb) }
        LOADB(b0, 0);
        LOADB(b1, 1); STEPF(b0, 0);
        LOADB(b0, 2); STEPF(b1, 1);
        LOADB(b1, 3); STEPF(b0, 2);
        STEPF(b1, 3);
        #undef STEPF
    } else {
        #define STEPS(buf, bb)                                                 \
            { float2 yb[8];                                                    \
              _Pragma("unroll")                                                \
              for (int k = 0; k < 8; ++k) {                                    \
                float dtv = buf[k].x, us = buf[k].y;                           \
                sdt += dtv;                                                    \
                float yv = 0.f;                                                \
                _Pragma("unroll")                                              \
                for (int jj = 0; jj < 4; ++jj) {                               \
                    float er = __expf(dtv * Are[jj]);                          \
                    float s, cc;                                               \
                    __sincosf(dtv * Aim[jj], &s, &cc);                         \
                    float ar = er * cc, ai = er * s;                           \
                    float gr = fmaf(ar, us, -us);                              \
                    float gi = ai * us;                                        \
                    float nr = fmaf(ar, sr[jj], fmaf(-ai, si[jj],              \
                                 fmaf(gr, BAr[jj], -gi * BAi[jj])));           \
                    float ni = fmaf(ar, si[jj], fmaf( ai, sr[jj],              \
                                 fmaf(gr, BAi[jj],  gi * BAr[jj])));           \
                    sr[jj] = nr; si[jj] = ni;                                  \
                    yv = fmaf(nr, Cre[jj], fmaf(-ni, Cim[jj], yv));            \
                }                                                              \
                yv += __shfl_xor(yv, 1);                                       \
                yv += __shfl_xor(yv, 2);                                       \
                yb[k] = make_float2(fmaf(dtv * us, Dv, yv), sdt);              \
              }                                                                \
              YWRITE(bb) }
        LOADB(b0, 0);
        LOADB(b1, 1); STEPS(b0, 0);
        LOADB(b0, 2); STEPS(b1, 1);
        LOADB(b1, 3); STEPS(b0, 2);
        STEPS(b1, 3);
        #undef STEPS
    }
    #undef LOADB
    #undef YWRITE

    int base = c * NCH + hnb;
    #pragma unroll
    for (int jj = 0; jj < 4; ++jj)
        Sb[base + jj] = make_float2(sr[jj], si[jj]);
    if (q == 0) Tc[hh * NCHUNK + c] = sdt;
}

// ---------------------------------------------------------------------------
// Kernel 3: fused prefix-combine. Block = {32 chains x 8 groups} (256 thr).
// P = exp(A*Tc) recomputed from the scalar Tc. Emits W[c][chain] = C * h0(c).
// ---------------------------------------------------------------------------
__global__ __launch_bounds__(256) void k_comb(const float2* __restrict__ Sb,
        const float* __restrict__ Tc, const float* __restrict__ A_log,
        const float* __restrict__ A_im, const float* __restrict__ C_param,
        float2* __restrict__ W) {
    __shared__ float4 agg_s[32][NGROUPS + 1];   // [chain_l][g], pad
    __shared__ float Tc_s[2][NCHUNK];
    const int t = threadIdx.x;
    const int g = t >> 5;                       // 0..7
    const int cl = t & 31;
    const int chain = blockIdx.x * 32 + cl;
    const int h0 = blockIdx.x * 2;              // block spans h0, h0+1

    {
        int cc = t & 127;
        int hs = t >> 7;
        Tc_s[hs][cc] = Tc[(h0 + hs) * NCHUNK + cc];
    }
    __syncthreads();

    const int hsel = cl >> 4;
    const float Are = -__expf(A_log[chain]);
    const float Aim = A_im[chain];

    float2 s[NGRP];
    float pr[NGRP], pi[NGRP];
    #pragma unroll
    for (int i = 0; i < NGRP; ++i) {
        int c = g * NGRP + i;
        s[i] = Sb[c * NCH + chain];
        float T = Tc_s[hsel][c];
        float er = __expf(Are * T);
        float sn, cs;
        __sincosf(Aim * T, &sn, &cs);
        pr[i] = er * cs;
        pi[i] = er * sn;
    }

    float Pr = 1.f, Pi = 0.f, Hr = 0.f, Hi = 0.f;
    #pragma unroll
    for (int i = 0; i < NGRP; ++i) {
        float nhr = fmaf(pr[i], Hr, fmaf(-pi[i], Hi, s[i].x));
        float nhi = fmaf(pr[i], Hi, fmaf( pi[i], Hr, s[i].y));
        float npr = fmaf(pr[i], Pr, -pi[i] * Pi);
        float npi = fmaf(pr[i], Pi,  pi[i] * Pr);
        Hr = nhr; Hi = nhi; Pr = npr; Pi = npi;
    }
    agg_s[cl][g] = make_float4(Pr, Pi, Hr, Hi);
    __syncthreads();

    // exclusive cross-group prefix (g uniform across each 32-lane slice)
    float hr = 0.f, hi = 0.f;
    for (int j = 0; j < g; ++j) {
        float4 a = agg_s[cl][j];
        float nr = fmaf(a.x, hr, fmaf(-a.y, hi, a.z));
        float ni = fmaf(a.x, hi, fmaf( a.y, hr, a.w));
        hr = nr; hi = ni;
    }

    const float Cr = C_param[2 * chain];
    const float Ci = C_param[2 * chain + 1];
    #pragma unroll
    for (int i = 0; i < NGRP; ++i) {
        int c = g * NGRP + i;
        W[c * NCH + chain] = make_float2(fmaf(Cr, hr, -Ci * hi),
                                         fmaf(Cr, hi,  Ci * hr));
        float nr = fmaf(pr[i], hr, fmaf(-pi[i], hi, s[i].x));
        float ni = fmaf(pr[i], hi, fmaf( pi[i], hr, s[i].y));
        hr = nr; hi = ni;
    }
}

// ---------------------------------------------------------------------------
// Kernel 4: correction pass. Thread owns one h x 8 l'; chunk-major y1T makes
// its 8 entries one contiguous 64-B block (4 float4); W row = 8 float4.
//   y = y1 + Re( sum_n exp(A_n*T_l) * W_n )
// ---------------------------------------------------------------------------
__global__ __launch_bounds__(256) void k_corr(const float2* __restrict__ y1T,
        const float* __restrict__ A_log, const float* __restrict__ A_im,
        const float2* __restrict__ W, float* __restrict__ out) {
    const int t = threadIdx.x;
    const int c = blockIdx.x;        // chunk
    const int hl = t & 63;
    const int h = blockIdx.y * 64 + hl;
    const int lb = t >> 6;           // 0..3
    const int l0 = c * CLEN + lb * 8;
    const int hn0 = h * N2d;

    float2 yt[8];
    {
        const float4* y4 = (const float4*)(y1T + ((size_t)c * Hd + h) * CLEN + lb * 8);
        #pragma unroll
        for (int i = 0; i < 4; ++i) {
            float4 v = y4[i];
            yt[2 * i]     = make_float2(v.x, v.y);
            yt[2 * i + 1] = make_float2(v.z, v.w);
        }
    }

    float2 w[N2d];
    {
        const float4* w4 = reinterpret_cast<const float4*>(&W[c * NCH + hn0]);
        #pragma unroll
        for (int n = 0; n < 8; ++n) {
            float4 v = w4[n];
            w[2 * n]     = make_float2(v.x, v.y);
            w[2 * n + 1] = make_float2(v.z, v.w);
        }
    }

    float alog[N2d], aim[N2d];
    #pragma unroll
    for (int n = 0; n < N2d; ++n) {
        alog[n] = A_log[hn0 + n];
        aim[n] = A_im[hn0 + n];
    }
    float dA = aim[1] - aim[0];
    bool fast = true;
    #pragma unroll
    for (int n = 1; n < N2d; ++n)
        fast = fast && (alog[n] == alog[0]) && (aim[n] - aim[n - 1] == dA);

    if (fast) {
        const float Are0 = -__expf(alog[0]);
        const float Aim0 = aim[0];
        #pragma unroll
        for (int k = 0; k < 8; ++k) {
            float T = yt[k].y;
            float er = __expf(Are0 * T);
            float s0, c0, sd, cd;
            __sincosf(Aim0 * T, &s0, &c0);
            __sincosf(dA * T, &sd, &cd);
            float ar = er * c0, ai = er * s0;
            float corr = 0.f;
            #pragma unroll
            for (int n = 0; n < N2d; ++n) {
                corr = fmaf(ar, w[n].x, fmaf(-ai, w[n].y, corr));
                if (n < N2d - 1) {
                    float tr = fmaf(ar, cd, -ai * sd);
                    ai = fmaf(ai, cd, ar * sd);
                    ar = tr;
                }
            }
            out[(l0 + k) * Hd + h] = yt[k].x + corr;
        }
    } else {
        float are[N2d];
        #pragma unroll
        for (int n = 0; n < N2d; ++n) are[n] = -__expf(alog[n]);
        #pragma unroll
        for (int k = 0; k < 8; ++k) {
            float T = yt[k].y;
            float corr = 0.f;
            #pragma unroll
            for (int n = 0; n < N2d; ++n) {
                float er = __expf(are[n] * T);
                float s, cc;
                __sincosf(aim[n] * T, &s, &cc);
                corr = fmaf(er * cc, w[n].x, fmaf(-er * s, w[n].y, corr));
            }
            out[(l0 + k) * Hd + h] = yt[k].x + corr;
        }
    }
}

extern "C" void kernel_launch(void* const* d_in, const int* in_sizes, int n_in,
                              void* d_out, int out_size, void* d_ws, size_t ws_size,
                              hipStream_t stream) {
    const float* u        = (const float*)d_in[0];
    const float* A_log    = (const float*)d_in[1];
    const float* A_im     = (const float*)d_in[2];
    const float* B_param  = (const float*)d_in[3];
    const float* C_param  = (const float*)d_in[4];
    const float* Dp       = (const float*)d_in[5];
    const float* dt_w     = (const float*)d_in[6];
    const float* dt_b     = (const float*)d_in[7];
    const float* xproj_w  = (const float*)d_in[8];

    // ws layout: du[L*H f2, chunk-major] | Sb[NCHUNK*NCH f2] | W[NCHUNK*NCH f2]
    //          | y1T[L*H f2, chunk-major] | Tc[Hd*NCHUNK f]
    float2* du  = (float2*)d_ws;
    float2* Sb  = du + (size_t)Ld * Hd;
    float2* W   = Sb + (size_t)NCHUNK * NCH;
    float2* y1T = W + (size_t)NCHUNK * NCH;
    float*  Tc  = (float*)(y1T + (size_t)Ld * Hd);
    float*  out = (float*)d_out;

    k_dt<<<Ld / 8, 256, 0, stream>>>(u, xproj_w, dt_w, dt_b, du);
    dim3 g2(NCHUNK, Hd / 64);
    k_chunk<<<g2, 256, 0, stream>>>(du, A_log, A_im, B_param, C_param, Dp,
                                    Sb, Tc, y1T);
    k_comb<<<NCH / 32, 256, 0, stream>>>(Sb, Tc, A_log, A_im, C_param, W);
    k_corr<<<g2, 256, 0, stream>>>(y1T, A_log, A_im, W, out);
}

// Round 16
// 128.041 us; speedup vs baseline: 1.0338x; 1.0182x over previous
//
#include <hip/hip_runtime.h>

#define Hd 512
#define N2d 16
#define Rd 32
#define Ld 4096
#define NCHUNK 128
#define CLEN (Ld / NCHUNK)        // 32
#define NCH (Hd * N2d)            // 8192 chains
#define NGRP 16                   // chunks per prefix group
#define NGROUPS (NCHUNK / NGRP)   // 8

// Layout notes:
//  - y1T is CHUNK-MAJOR [c][h][l'] (contiguous 64-B rows for k_chunk/k_corr).
//  - du is GONE (r16): k_dtu emits only the 0.5 MB einsum1 waist (dtu[l][r]);
//    k_chunk recomputes dt/us on-chip (einsum2+softplus into LDS). Removes
//    the 67 MB du round-trip at the cost of ~13 MB (u re-read + dtu reuse).

// ---------------------------------------------------------------------------
// Kernel 1: einsum1 only: dtu[l][r] = sum_h u[l][h] * xproj_w[r][h].
// ---------------------------------------------------------------------------
__global__ __launch_bounds__(256) void k_dtu(const float* __restrict__ u,
                                             const float* __restrict__ xproj_w,
                                             float* __restrict__ dtu) {
    __shared__ float u_s[8][Hd];
    const int t = threadIdx.x;
    const int l0 = blockIdx.x * 8;

    #pragma unroll
    for (int i = 0; i < 16; ++i) {
        int idx = t + i * 256;
        ((float*)u_s)[idx] = u[l0 * Hd + idx];
    }
    __syncthreads();

    const int r = t >> 3;
    const int j = t & 7;
    float part[8];
    #pragma unroll
    for (int l = 0; l < 8; ++l) part[l] = 0.f;
    for (int k = 0; k < 64; ++k) {
        float w = xproj_w[r * Hd + k * 8 + j];
        #pragma unroll
        for (int l = 0; l < 8; ++l) part[l] = fmaf(u_s[l][k * 8 + j], w, part[l]);
    }
    #pragma unroll
    for (int off = 1; off < 8; off <<= 1) {
        #pragma unroll
        for (int l = 0; l < 8; ++l) part[l] += __shfl_xor(part[l], off);
    }
    if (j == 0) {
        #pragma unroll
        for (int l = 0; l < 8; ++l) dtu[(l0 + l) * Rd + r] = part[l];
    }
}

// ---------------------------------------------------------------------------
// Kernel 2: fused dt+scan. Block = (chunk c, 64-h group).
// Phase A: stage u-tile (8 KB) + dtu-tile (4 KB) -> compute dt = softplus(
//          dtu@dt_wT + b), us = u/dt into du_s (16 KB LDS). Same FMA order
//          as the old k_dt (bit-identical).
// Phase B: r15 scan reading du_s (quad-broadcast LDS, conflict-free).
// Emits Sb (float2) + Tc (chunk dt-sum) + y1T[c][h][l'] = (y1, T_l).
// ---------------------------------------------------------------------------
__global__ __launch_bounds__(256) void k_chunk(const float* __restrict__ u,
        const float* __restrict__ dtu, const float* __restrict__ dt_w,
        const float* __restrict__ dt_b,
        const float* __restrict__ A_log, const float* __restrict__ A_im,
        const float* __restrict__ B_param, const float* __restrict__ C_param,
        const float* __restrict__ Dp,
        float2* __restrict__ Sb, float* __restrict__ Tc,
        float2* __restrict__ y1T) {
    __shared__ float u_s[CLEN][64];       // 8 KB   [l'][hl]
    __shared__ float dtu_s[CLEN][Rd];     // 4 KB   [l'][r]
    __shared__ float2 du_s[CLEN][64];     // 16 KB  [l'][hl]
    const int t = threadIdx.x;
    const int c = blockIdx.x;
    const int hg = blockIdx.y;

    // ---- stage u tile: 32 rows x 64 floats (4 rows/wave-instr, 256-B segs)
    {
        const float* ub = u + (size_t)(c * CLEN) * Hd + hg * 64;
        #pragma unroll
        for (int i = 0; i < 2; ++i) {
            int idx = i * 256 + t;            // 0..511
            int row = idx >> 4;               // 16 float4 per row
            int col = idx & 15;
            *(float4*)&u_s[row][col * 4] = *(const float4*)(ub + (size_t)row * Hd + col * 4);
        }
    }
    // ---- stage dtu tile: 32 rows x 32 r = 4 KB contiguous (1 float4/thread)
    {
        const float4* db = (const float4*)(dtu + (size_t)c * CLEN * Rd);
        *(((float4*)dtu_s) + t) = db[t];
    }
    __syncthreads();

    // ---- Phase A: dt/us for 8 (l, h) pairs per thread (h = t&63, 8 l's)
    {
        const int hl2 = t & 63;
        const int h = hg * 64 + hl2;
        const int lb2 = t >> 6;               // 0..3
        const float bias = dt_b[h];
        const float4* w4 = (const float4*)&dt_w[h * Rd];
        float acc[8];
        #pragma unroll
        for (int k = 0; k < 8; ++k) acc[k] = bias;
        #pragma unroll
        for (int rb = 0; rb < 8; ++rb) {
            float4 w = w4[rb];
            #pragma unroll
            for (int k = 0; k < 8; ++k) {
                int l = lb2 * 8 + k;
                acc[k] = fmaf(dtu_s[l][rb * 4 + 0], w.x, acc[k]);
                acc[k] = fmaf(dtu_s[l][rb * 4 + 1], w.y, acc[k]);
                acc[k] = fmaf(dtu_s[l][rb * 4 + 2], w.z, acc[k]);
                acc[k] = fmaf(dtu_s[l][rb * 4 + 3], w.w, acc[k]);
            }
        }
        #pragma unroll
        for (int k = 0; k < 8; ++k) {
            int l = lb2 * 8 + k;
            float x = acc[k];
            float sp = fmaxf(x, 0.f) + log1pf(__expf(-fabsf(x)));  // softplus
            float uv = u_s[l][hl2];
            float us = uv * __builtin_amdgcn_rcpf(fmaxf(sp, 1e-30f));
            du_s[l][hl2] = make_float2(sp, us);
        }
    }
    __syncthreads();

    // ---- Phase B: scan (r15 structure, operands from LDS) ----
    const int q = t & 3;
    const int hl = t >> 2;                    // 0..63
    const int hh = hg * 64 + hl;
    const int hnb = hh * N2d + q * 4;
    float2* y1row = y1T + ((size_t)c * Hd + hh) * CLEN;

    float alog[4], Aim[4];
    #pragma unroll
    for (int j = 0; j < 4; ++j) {
        alog[j] = A_log[hnb + j];
        Aim[j] = A_im[hnb + j];
    }
    float d1 = Aim[1] - Aim[0], d2 = Aim[2] - Aim[1], d3 = Aim[3] - Aim[2];
    const bool fast = (alog[1] == alog[0]) && (alog[2] == alog[0]) &&
                      (alog[3] == alog[0]) && (d1 == d2) && (d2 == d3);
    float Are[4];
    if (fast) {
        Are[0] = -__expf(alog[0]);
        Are[1] = Are[2] = Are[3] = Are[0];
    } else {
        #pragma unroll
        for (int j = 0; j < 4; ++j) Are[j] = -__expf(alog[j]);
    }
    float BAr[4], BAi[4], Cre[4], Cim[4];
    #pragma unroll
    for (int j = 0; j < 4; ++j) {
        int hn = hnb + j;
        float Bre = B_param[2 * hn];
        float Bim = B_param[2 * hn + 1];
        float inv = __builtin_amdgcn_rcpf(Are[j] * Are[j] + Aim[j] * Aim[j]);
        BAr[j] = (Bre * Are[j] + Bim * Aim[j]) * inv;   // Bc*conj(A)/|A|^2
        BAi[j] = (Bim * Are[j] - Bre * Aim[j]) * inv;
        Cre[j] = C_param[2 * hn];
        Cim[j] = C_param[2 * hn + 1];
    }
    const float Dv = Dp[hh];

    float sr[4] = {0.f, 0.f, 0.f, 0.f}, si[4] = {0.f, 0.f, 0.f, 0.f};
    float sdt = 0.f;

    #define YWRITE(bb)                                                         \
        if (q == 0) {                                                          \
            float4* y4 = (float4*)(y1row + (bb) * 8);                          \
            _Pragma("unroll")                                                  \
            for (int i = 0; i < 4; ++i)                                        \
                y4[i] = make_float4(yb[2 * i].x, yb[2 * i].y,                  \
                                    yb[2 * i + 1].x, yb[2 * i + 1].y);         \
        }

    if (fast) {
        const float Are0 = Are[0], Aim0 = Aim[0], dA = Aim[1] - Aim[0];
        #pragma unroll
        for (int bb = 0; bb < 4; ++bb) {
            float2 yb[8];
            #pragma unroll
            for (int k = 0; k < 8; ++k) {
                float2 d = du_s[bb * 8 + k][hl];
                float dtv = d.x, us = d.y;
                sdt += dtv;
                float er = __expf(dtv * Are0);
                float s0, c0, sd, cd;
                __sincosf(dtv * Aim0, &s0, &c0);
                __sincosf(dtv * dA, &sd, &cd);
                float ar = er * c0, ai = er * s0;
                float yv = 0.f;
                #pragma unroll
                for (int jj = 0; jj < 4; ++jj) {
                    float gr = fmaf(ar, us, -us);
                    float gi = ai * us;
                    float nr = fmaf(ar, sr[jj], fmaf(-ai, si[jj],
                                 fmaf(gr, BAr[jj], -gi * BAi[jj])));
                    float ni = fmaf(ar, si[jj], fmaf( ai, sr[jj],
                                 fmaf(gr, BAi[jj],  gi * BAr[jj])));
                    sr[jj] = nr; si[jj] = ni;
                    yv = fmaf(nr, Cre[jj], fmaf(-ni, Cim[jj], yv));
                    if (jj < 3) {
                        float tr = fmaf(ar, cd, -ai * sd);
                        ai = fmaf(ai, cd, ar * sd);
                        ar = tr;
                    }
                }
                yv += __shfl_xor(yv, 1);
                yv += __shfl_xor(yv, 2);
                yb[k] = make_float2(fmaf(dtv * us, Dv, yv), sdt);
            }
            YWRITE(bb)
        }
    } else {
        #pragma unroll
        for (int bb = 0; bb < 4; ++bb) {
            float2 yb[8];
            #pragma unroll
            for (int k = 0; k < 8; ++k) {
                float2 d = du_s[bb * 8 + k][hl];
                float dtv = d.x, us = d.y;
                sdt += dtv;
                float yv = 0.f;
                #pragma unroll
                for (int jj = 0; jj < 4; ++jj) {
                    float er = __expf(dtv * Are[jj]);
                    float s, cc;
                    __sincosf(dtv * Aim[jj], &s, &cc);
                    float ar = er * cc, ai = er * s;
                    float gr = fmaf(ar, us, -us);
                    float gi = ai * us;
                    float nr = fmaf(ar, sr[jj], fmaf(-ai, si[jj],
                                 fmaf(gr, BAr[jj], -gi * BAi[jj])));
                    float ni = fmaf(ar, si[jj], fmaf( ai, sr[jj],
                                 fmaf(gr, BAi[jj],  gi * BAr[jj])));
                    sr[jj] = nr; si[jj] = ni;
                    yv = fmaf(nr, Cre[jj], fmaf(-ni, Cim[jj], yv));
                }
                yv += __shfl_xor(yv, 1);
                yv += __shfl_xor(yv, 2);
                yb[k] = make_float2(fmaf(dtv * us, Dv, yv), sdt);
            }
            YWRITE(bb)
        }
    }
    #undef YWRITE

    int base = c * NCH + hnb;
    #pragma unroll
    for (int jj = 0; jj < 4; ++jj)
        Sb[base + jj] = make_float2(sr[jj], si[jj]);
    if (q == 0) Tc[hh * NCHUNK + c] = sdt;
}

// ---------------------------------------------------------------------------
// Kernel 3: fused prefix-combine. Block = {32 chains x 8 groups} (256 thr).
// P = exp(A*Tc) recomputed from the scalar Tc. Emits W[c][chain] = C * h0(c).
// ---------------------------------------------------------------------------
__global__ __launch_bounds__(256) void k_comb(const float2* __restrict__ Sb,
        const float* __restrict__ Tc, const float* __restrict__ A_log,
        const float* __restrict__ A_im, const float* __restrict__ C_param,
        float2* __restrict__ W) {
    __shared__ float4 agg_s[32][NGROUPS + 1];   // [chain_l][g], pad
    __shared__ float Tc_s[2][NCHUNK];
    const int t = threadIdx.x;
    const int g = t >> 5;                       // 0..7
    const int cl = t & 31;
    const int chain = blockIdx.x * 32 + cl;
    const int h0 = blockIdx.x * 2;              // block spans h0, h0+1

    {
        int cc = t & 127;
        int hs = t >> 7;
        Tc_s[hs][cc] = Tc[(h0 + hs) * NCHUNK + cc];
    }
    __syncthreads();

    const int hsel = cl >> 4;
    const float Are = -__expf(A_log[chain]);
    const float Aim = A_im[chain];

    float2 s[NGRP];
    float pr[NGRP], pi[NGRP];
    #pragma unroll
    for (int i = 0; i < NGRP; ++i) {
        int c = g * NGRP + i;
        s[i] = Sb[c * NCH + chain];
        float T = Tc_s[hsel][c];
        float er = __expf(Are * T);
        float sn, cs;
        __sincosf(Aim * T, &sn, &cs);
        pr[i] = er * cs;
        pi[i] = er * sn;
    }

    float Pr = 1.f, Pi = 0.f, Hr = 0.f, Hi = 0.f;
    #pragma unroll
    for (int i = 0; i < NGRP; ++i) {
        float nhr = fmaf(pr[i], Hr, fmaf(-pi[i], Hi, s[i].x));
        float nhi = fmaf(pr[i], Hi, fmaf( pi[i], Hr, s[i].y));
        float npr = fmaf(pr[i], Pr, -pi[i] * Pi);
        float npi = fmaf(pr[i], Pi,  pi[i] * Pr);
        Hr = nhr; Hi = nhi; Pr = npr; Pi = npi;
    }
    agg_s[cl][g] = make_float4(Pr, Pi, Hr, Hi);
    __syncthreads();

    // exclusive cross-group prefix (g uniform across each 32-lane slice)
    float hr = 0.f, hi = 0.f;
    for (int j = 0; j < g; ++j) {
        float4 a = agg_s[cl][j];
        float nr = fmaf(a.x, hr, fmaf(-a.y, hi, a.z));
        float ni = fmaf(a.x, hi, fmaf( a.y, hr, a.w));
        hr = nr; hi = ni;
    }

    const float Cr = C_param[2 * chain];
    const float Ci = C_param[2 * chain + 1];
    #pragma unroll
    for (int i = 0; i < NGRP; ++i) {
        int c = g * NGRP + i;
        W[c * NCH + chain] = make_float2(fmaf(Cr, hr, -Ci * hi),
                                         fmaf(Cr, hi,  Ci * hr));
        float nr = fmaf(pr[i], hr, fmaf(-pi[i], hi, s[i].x));
        float ni = fmaf(pr[i], hi, fmaf( pi[i], hr, s[i].y));
        hr = nr; hi = ni;
    }
}

// ---------------------------------------------------------------------------
// Kernel 4: correction pass. Thread owns one h x 8 l'; chunk-major y1T makes
// its 8 entries one contiguous 64-B block (4 float4); W row = 8 float4.
//   y = y1 + Re( sum_n exp(A_n*T_l) * W_n )
// ---------------------------------------------------------------------------
__global__ __launch_bounds__(256) void k_corr(const float2* __restrict__ y1T,
        const float* __restrict__ A_log, const float* __restrict__ A_im,
        const float2* __restrict__ W, float* __restrict__ out) {
    const int t = threadIdx.x;
    const int c = blockIdx.x;        // chunk
    const int hl = t & 63;
    const int h = blockIdx.y * 64 + hl;
    const int lb = t >> 6;           // 0..3
    const int l0 = c * CLEN + lb * 8;
    const int hn0 = h * N2d;

    float2 yt[8];
    {
        const float4* y4 = (const float4*)(y1T + ((size_t)c * Hd + h) * CLEN + lb * 8);
        #pragma unroll
        for (int i = 0; i < 4; ++i) {
            float4 v = y4[i];
            yt[2 * i]     = make_float2(v.x, v.y);
            yt[2 * i + 1] = make_float2(v.z, v.w);
        }
    }

    float2 w[N2d];
    {
        const float4* w4 = reinterpret_cast<const float4*>(&W[c * NCH + hn0]);
        #pragma unroll
        for (int n = 0; n < 8; ++n) {
            float4 v = w4[n];
            w[2 * n]     = make_float2(v.x, v.y);
            w[2 * n + 1] = make_float2(v.z, v.w);
        }
    }

    float alog[N2d], aim[N2d];
    #pragma unroll
    for (int n = 0; n < N2d; ++n) {
        alog[n] = A_log[hn0 + n];
        aim[n] = A_im[hn0 + n];
    }
    float dA = aim[1] - aim[0];
    bool fast = true;
    #pragma unroll
    for (int n = 1; n < N2d; ++n)
        fast = fast && (alog[n] == alog[0]) && (aim[n] - aim[n - 1] == dA);

    if (fast) {
        const float Are0 = -__expf(alog[0]);
        const float Aim0 = aim[0];
        #pragma unroll
        for (int k = 0; k < 8; ++k) {
            float T = yt[k].y;
            float er = __expf(Are0 * T);
            float s0, c0, sd, cd;
            __sincosf(Aim0 * T, &s0, &c0);
            __sincosf(dA * T, &sd, &cd);
            float ar = er * c0, ai = er * s0;
            float corr = 0.f;
            #pragma unroll
            for (int n = 0; n < N2d; ++n) {
                corr = fmaf(ar, w[n].x, fmaf(-ai, w[n].y, corr));
                if (n < N2d - 1) {
                    float tr = fmaf(ar, cd, -ai * sd);
                    ai = fmaf(ai, cd, ar * sd);
                    ar = tr;
                }
            }
            out[(l0 + k) * Hd + h] = yt[k].x + corr;
        }
    } else {
        float are[N2d];
        #pragma unroll
        for (int n = 0; n < N2d; ++n) are[n] = -__expf(alog[n]);
        #pragma unroll
        for (int k = 0; k < 8; ++k) {
            float T = yt[k].y;
            float corr = 0.f;
            #pragma unroll
            for (int n = 0; n < N2d; ++n) {
                float er = __expf(are[n] * T);
                float s, cc;
                __sincosf(aim[n] * T, &s, &cc);
                corr = fmaf(er * cc, w[n].x, fmaf(-er * s, w[n].y, corr));
            }
            out[(l0 + k) * Hd + h] = yt[k].x + corr;
        }
    }
}

extern "C" void kernel_launch(void* const* d_in, const int* in_sizes, int n_in,
                              void* d_out, int out_size, void* d_ws, size_t ws_size,
                              hipStream_t stream) {
    const float* u        = (const float*)d_in[0];
    const float* A_log    = (const float*)d_in[1];
    const float* A_im     = (const float*)d_in[2];
    const float* B_param  = (const float*)d_in[3];
    const float* C_param  = (const float*)d_in[4];
    const float* Dp       = (const float*)d_in[5];
    const float* dt_w     = (const float*)d_in[6];
    const float* dt_b     = (const float*)d_in[7];
    const float* xproj_w  = (const float*)d_in[8];

    // ws layout: dtu[L*R f] | Sb[NCHUNK*NCH f2] | W[NCHUNK*NCH f2]
    //          | y1T[L*H f2, chunk-major] | Tc[Hd*NCHUNK f]
    float*  dtu = (float*)d_ws;
    float2* Sb  = (float2*)(dtu + (size_t)Ld * Rd);
    float2* W   = Sb + (size_t)NCHUNK * NCH;
    float2* y1T = W + (size_t)NCHUNK * NCH;
    float*  Tc  = (float*)(y1T + (size_t)Ld * Hd);
    float*  out = (float*)d_out;

    k_dtu<<<Ld / 8, 256, 0, stream>>>(u, xproj_w, dtu);
    dim3 g2(NCHUNK, Hd / 64);
    k_chunk<<<g2, 256, 0, stream>>>(u, dtu, dt_w, dt_b, A_log, A_im,
                                    B_param, C_param, Dp, Sb, Tc, y1T);
    k_comb<<<NCH / 32, 256, 0, stream>>>(Sb, Tc, A_log, A_im, C_param, W);
    k_corr<<<g2, 256, 0, stream>>>(y1T, A_log, A_im, W, out);
}